// Round 1
// baseline (209.072 us; speedup 1.0000x reference)
//
#include <hip/hip_runtime.h>

// n = 8192 points, d = 512, fp32 in, scalar fp32 out.
// Pipeline: (1) fp32->bf16 convert, (2) fused bf16-MFMA GEMM + per-row argmax
// (diagonal masked, N split 8 ways), (3) combine partial argmaxes,
// (4) per-row ||x - x[I] + 1e-6||_2 -> log, (5) deterministic mean reduce.

#define NPTS 8192
#define DIM  512
#define BM   128
#define BN   128
#define BK   32
#define NSPLIT 8
#define NT_PER_SPLIT (NPTS / NSPLIT / BN)   // 8 N-tiles of 128 per split

typedef __bf16 bf16x8 __attribute__((ext_vector_type(8)));
typedef float  f32x4  __attribute__((ext_vector_type(4)));

__device__ __forceinline__ unsigned short f32_to_bf16(float f) {
  unsigned int u = __builtin_bit_cast(unsigned int, f);
  u += 0x7fffu + ((u >> 16) & 1u);   // round-to-nearest-even
  return (unsigned short)(u >> 16);
}

__global__ void cvt_bf16_kernel(const float* __restrict__ x,
                                unsigned short* __restrict__ xb) {
  int i = blockIdx.x * blockDim.x + threadIdx.x;      // 4 elems per thread
  float4 v = reinterpret_cast<const float4*>(x)[i];
  ushort4 o;
  o.x = f32_to_bf16(v.x); o.y = f32_to_bf16(v.y);
  o.z = f32_to_bf16(v.z); o.w = f32_to_bf16(v.w);
  reinterpret_cast<ushort4*>(xb)[i] = o;
}

__device__ __forceinline__ void gload_lds16(const unsigned short* g,
                                            unsigned short* l) {
  __builtin_amdgcn_global_load_lds(
      (__attribute__((address_space(1))) const void*)g,
      (__attribute__((address_space(3))) void*)l, 16, 0, 0);
}

// Fused GEMM (scores = Xrows . Xcols^T in bf16) + running argmax per row.
// grid = (NPTS/BM, NSPLIT), block = 256 (4 waves, 2x2 wave grid of 64x64).
__global__ __launch_bounds__(256) void argmax_gemm_kernel(
    const unsigned short* __restrict__ xb,
    float* __restrict__ pval, int* __restrict__ pidx) {
  __shared__ unsigned short As[BM * BK];   // 8 KB
  __shared__ unsigned short Bs[BN * BK];   // 8 KB

  const int tid  = threadIdx.x;
  const int wave = tid >> 6;
  const int lane = tid & 63;
  const int wr   = wave >> 1;      // wave row half (0..1)
  const int wc   = wave & 1;       // wave col half (0..1)
  const int l15  = lane & 15;
  const int l16  = lane >> 4;      // 0..3

  const int mrow0 = blockIdx.x * BM;
  const int split = blockIdx.y;

  float best[16];
  int   bidx[16];
#pragma unroll
  for (int i = 0; i < 16; ++i) { best[i] = -1e30f; bidx[i] = 0; }

  for (int nt = 0; nt < NT_PER_SPLIT; ++nt) {
    const int ncol0 = split * (NPTS / NSPLIT) + nt * BN;

    f32x4 acc[4][4];
#pragma unroll
    for (int mi = 0; mi < 4; ++mi)
#pragma unroll
      for (int ni = 0; ni < 4; ++ni)
        acc[mi][ni] = (f32x4){0.f, 0.f, 0.f, 0.f};

    for (int kt = 0; kt < DIM / BK; ++kt) {
      const int k0 = kt * BK;
      __syncthreads();   // previous iteration's LDS reads complete
#pragma unroll
      for (int r = 0; r < 2; ++r) {
        const int chunk = (r << 8) + tid;          // 0..511 (16B chunks)
        const int row   = chunk >> 2;              // 0..127
        const int kc    = (chunk & 3) << 3;        // 0,8,16,24
        const int lbase = ((r << 8) + (wave << 6)) << 3;  // elems, wave-uniform
        gload_lds16(xb + (size_t)(mrow0 + row) * DIM + k0 + kc, As + lbase);
        gload_lds16(xb + (size_t)(ncol0 + row) * DIM + k0 + kc, Bs + lbase);
      }
      __syncthreads();   // implies vmcnt(0): staged data visible

      bf16x8 af[4], bf[4];
#pragma unroll
      for (int mi = 0; mi < 4; ++mi)
        af[mi] = *reinterpret_cast<const bf16x8*>(
            &As[(wr * 64 + mi * 16 + l15) * BK + (l16 << 3)]);
#pragma unroll
      for (int ni = 0; ni < 4; ++ni)
        bf[ni] = *reinterpret_cast<const bf16x8*>(
            &Bs[(wc * 64 + ni * 16 + l15) * BK + (l16 << 3)]);
#pragma unroll
      for (int mi = 0; mi < 4; ++mi)
#pragma unroll
        for (int ni = 0; ni < 4; ++ni)
          acc[mi][ni] = __builtin_amdgcn_mfma_f32_16x16x32_bf16(
              af[mi], bf[ni], acc[mi][ni], 0, 0, 0);
    }

    // Running argmax update for this N-tile.
    // C/D layout: col = lane&15, row = (lane>>4)*4 + reg.
#pragma unroll
    for (int mi = 0; mi < 4; ++mi)
#pragma unroll
      for (int j = 0; j < 4; ++j) {
        const int slot = mi * 4 + j;
        const int grow = mrow0 + wr * 64 + mi * 16 + l16 * 4 + j;
#pragma unroll
        for (int ni = 0; ni < 4; ++ni) {
          float v = acc[mi][ni][j];
          const int gcol = ncol0 + wc * 64 + ni * 16 + l15;
          if (gcol == grow) v = -1e30f;            // mask diagonal
          if (v > best[slot] || (v == best[slot] && gcol < bidx[slot])) {
            best[slot] = v; bidx[slot] = gcol;
          }
        }
      }
  }

  // Reduce across the 16 lanes that share each row (same lane>>4 group).
#pragma unroll
  for (int m = 1; m < 16; m <<= 1) {
#pragma unroll
    for (int slot = 0; slot < 16; ++slot) {
      float ov = __shfl_xor(best[slot], m);
      int   oi = __shfl_xor(bidx[slot], m);
      if (ov > best[slot] || (ov == best[slot] && oi < bidx[slot])) {
        best[slot] = ov; bidx[slot] = oi;
      }
    }
  }

  if (l15 == 0) {
#pragma unroll
    for (int mi = 0; mi < 4; ++mi)
#pragma unroll
      for (int j = 0; j < 4; ++j) {
        const int slot = mi * 4 + j;
        const int grow = mrow0 + wr * 64 + mi * 16 + l16 * 4 + j;
        pval[grow * NSPLIT + split] = best[slot];
        pidx[grow * NSPLIT + split] = bidx[slot];
      }
  }
}

// Merge the NSPLIT partial argmaxes per row (ascending split = ascending col
// ranges -> first-occurrence tie-breaking preserved).
__global__ void combine_kernel(const float* __restrict__ pval,
                               const int* __restrict__ pidx,
                               int* __restrict__ nnidx) {
  int r = blockIdx.x * blockDim.x + threadIdx.x;
  float bv = -1e30f; int bi = 0;
#pragma unroll
  for (int s = 0; s < NSPLIT; ++s) {
    float v = pval[r * NSPLIT + s];
    int   i = pidx[r * NSPLIT + s];
    if (v > bv || (v == bv && i < bi)) { bv = v; bi = i; }
  }
  nnidx[r] = bi;
}

// rho_r = ||x_r - x_{nn(r)} + 1e-6||_2 ; logs[r] = log(rho + 1e-8).
// One wave per row, 4 rows per 256-thread block.
__global__ void dist_log_kernel(const float* __restrict__ x,
                                const int* __restrict__ nnidx,
                                float* __restrict__ logs) {
  const int row  = blockIdx.x * 4 + (threadIdx.x >> 6);
  const int lane = threadIdx.x & 63;
  const int nn   = nnidx[row];
  const float4* xr = reinterpret_cast<const float4*>(x + (size_t)row * DIM);
  const float4* xn = reinterpret_cast<const float4*>(x + (size_t)nn  * DIM);
  float s = 0.f;
#pragma unroll
  for (int i = 0; i < 2; ++i) {
    float4 a = xr[lane + i * 64];
    float4 b = xn[lane + i * 64];
    float d0 = a.x - b.x + 1e-6f;
    float d1 = a.y - b.y + 1e-6f;
    float d2 = a.z - b.z + 1e-6f;
    float d3 = a.w - b.w + 1e-6f;
    s += d0 * d0 + d1 * d1 + d2 * d2 + d3 * d3;
  }
#pragma unroll
  for (int m = 32; m >= 1; m >>= 1) s += __shfl_xor(s, m);
  if (lane == 0) logs[row] = logf(sqrtf(s) + 1e-8f);
}

// Deterministic mean: 1024 threads x 8 sequential adds + LDS tree.
__global__ void final_reduce_kernel(const float* __restrict__ logs,
                                    float* __restrict__ out) {
  __shared__ float sm[1024];
  const int t = threadIdx.x;
  float s = 0.f;
#pragma unroll
  for (int i = 0; i < 8; ++i) s += logs[t * 8 + i];
  sm[t] = s;
  __syncthreads();
  for (int k = 512; k > 0; k >>= 1) {
    if (t < k) sm[t] += sm[t + k];
    __syncthreads();
  }
  if (t == 0) out[0] = -(sm[0] / (float)NPTS);
}

extern "C" void kernel_launch(void* const* d_in, const int* in_sizes, int n_in,
                              void* d_out, int out_size, void* d_ws, size_t ws_size,
                              hipStream_t stream) {
  const float* x = (const float*)d_in[0];
  float* out = (float*)d_out;
  char* ws = (char*)d_ws;

  // Workspace layout (bytes):
  unsigned short* xb    = (unsigned short*)(ws);            // 8192*512*2 = 8 MB
  float*          pval  = (float*)(ws + 8388608);           // 8192*8*4 = 256 KB
  int*            pidx  = (int*)  (ws + 8650752);           // 256 KB
  int*            nnidx = (int*)  (ws + 8912896);           // 32 KB
  float*          logs  = (float*)(ws + 8945664);           // 32 KB

  cvt_bf16_kernel<<<(NPTS * DIM / 4) / 256, 256, 0, stream>>>(x, xb);

  dim3 g(NPTS / BM, NSPLIT);
  argmax_gemm_kernel<<<g, 256, 0, stream>>>(xb, pval, pidx);

  combine_kernel<<<NPTS / 256, 256, 0, stream>>>(pval, pidx, nnidx);

  dist_log_kernel<<<NPTS / 4, 256, 0, stream>>>(x, nnidx, logs);

  final_reduce_kernel<<<1, 1024, 0, stream>>>(logs, out);
}

// Round 2
// 124.454 us; speedup vs baseline: 1.6799x; 1.6799x over previous
//
#include <hip/hip_runtime.h>

// n = 8192 points, d = 512, fp32 in, scalar fp32 out.
// Pipeline:
//   (1) fp32->bf16 convert (+ zero-init packed argmax keys)
//   (2) lower-triangular fused bf16-MFMA GEMM: each 128x128 tile (ti>=tj)
//       updates BOTH per-row and per-col argmax via deterministic u64
//       atomicMax of (monotone(value)<<32 | ~index)  [symmetry halves MFMA]
//   (3) per-row ||x - x[I] + 1e-6||_2 -> log
//   (4) deterministic mean reduce.

#define NPTS 8192
#define DIM  512
#define BM   128
#define BN   128
#define BK   32
#define NTIL (NPTS / BM)            // 64 tiles per dim
#define NBLK (NTIL * (NTIL + 1) / 2) // 2080 lower-tri tile pairs
#define KT_STEPS (DIM / BK)          // 16

typedef __bf16 bf16x8 __attribute__((ext_vector_type(8)));
typedef float  f32x4  __attribute__((ext_vector_type(4)));

__device__ __forceinline__ unsigned short f32_to_bf16(float f) {
  unsigned int u = __builtin_bit_cast(unsigned int, f);
  u += 0x7fffu + ((u >> 16) & 1u);   // round-to-nearest-even
  return (unsigned short)(u >> 16);
}

// Order-preserving f32 -> u32 (total order, matches float compare on reals).
__device__ __forceinline__ unsigned int mono_f32(float f) {
  unsigned int u = __builtin_bit_cast(unsigned int, f);
  return (u & 0x80000000u) ? ~u : (u | 0x80000000u);
}

__global__ void cvt_bf16_kernel(const float* __restrict__ x,
                                unsigned short* __restrict__ xb,
                                unsigned long long* __restrict__ nn64) {
  int i = blockIdx.x * blockDim.x + threadIdx.x;      // 4 elems per thread
  float4 v = reinterpret_cast<const float4*>(x)[i];
  ushort4 o;
  o.x = f32_to_bf16(v.x); o.y = f32_to_bf16(v.y);
  o.z = f32_to_bf16(v.z); o.w = f32_to_bf16(v.w);
  reinterpret_cast<ushort4*>(xb)[i] = o;
  if (i < NPTS) nn64[i] = 0ull;                       // argmax key init
}

__device__ __forceinline__ void gload_lds16(const unsigned short* g,
                                            unsigned short* l) {
  __builtin_amdgcn_global_load_lds(
      (__attribute__((address_space(1))) const void*)g,
      (__attribute__((address_space(3))) void*)l, 16, 0, 0);
}

__device__ __forceinline__ unsigned long long kmax(unsigned long long a,
                                                   unsigned long long b) {
  return a > b ? a : b;
}

// Lower-triangular fused GEMM + dual argmax.
// grid = NBLK, block = 256 (4 waves in a 2x2 grid of 64x64 sub-tiles).
__global__ __launch_bounds__(256) void tri_gemm_kernel(
    const unsigned short* __restrict__ xb,
    unsigned long long* __restrict__ nn64) {
  __shared__ unsigned short As[2][BM * BK];   // 2 x 8 KB
  __shared__ unsigned short Bs[2][BN * BK];   // 2 x 8 KB

  // blockIdx -> (ti >= tj) triangular mapping.
  const int t = blockIdx.x;
  int ti = (int)((sqrtf(8.0f * (float)t + 1.0f) - 1.0f) * 0.5f);
  while ((ti + 1) * (ti + 2) / 2 <= t) ++ti;
  while (ti * (ti + 1) / 2 > t) --ti;
  const int tj = t - ti * (ti + 1) / 2;

  const int tid  = threadIdx.x;
  const int wave = tid >> 6;
  const int lane = tid & 63;
  const int wr   = wave >> 1;      // wave row half (0..1)
  const int wc   = wave & 1;       // wave col half (0..1)
  const int l15  = lane & 15;
  const int l16  = lane >> 4;      // 0..3

  const int mrow0 = ti * BM;
  const int ncol0 = tj * BN;

  // Stage K-step kt into buffer b. LDS dest is linear (wave-uniform base,
  // lane x 16B); bank-conflict-free reads come from pre-swizzling the
  // GLOBAL source column chunk: sg = s ^ ((row>>1)&3)  (involution).
#define STAGE(b, kt)                                                         \
  do {                                                                       \
    const int k0_ = (kt) * BK;                                               \
    _Pragma("unroll")                                                        \
    for (int r_ = 0; r_ < 2; ++r_) {                                         \
      const int chunk_ = (r_ << 8) + tid;          /* 0..511 (16B chunks) */ \
      const int row_   = chunk_ >> 2;              /* 0..127 */              \
      const int s_     = chunk_ & 3;                                         \
      const int sg_    = s_ ^ ((row_ >> 1) & 3);                             \
      const int lbase_ = ((r_ << 8) + (wave << 6)) << 3; /* wave-uniform */  \
      gload_lds16(xb + (size_t)(mrow0 + row_) * DIM + k0_ + (sg_ << 3),      \
                  &As[b][lbase_]);                                           \
      gload_lds16(xb + (size_t)(ncol0 + row_) * DIM + k0_ + (sg_ << 3),      \
                  &Bs[b][lbase_]);                                           \
    }                                                                        \
  } while (0)

  f32x4 acc[4][4];
#pragma unroll
  for (int mi = 0; mi < 4; ++mi)
#pragma unroll
    for (int ni = 0; ni < 4; ++ni)
      acc[mi][ni] = (f32x4){0.f, 0.f, 0.f, 0.f};

  const int swz = (l15 >> 1) & 3;   // read-side XOR: rows base are x16 => even

  STAGE(0, 0);
  __syncthreads();                  // drain vmcnt(0): buf0 ready

  for (int kt = 0; kt < KT_STEPS; ++kt) {
    const int cur = kt & 1;
    if (kt + 1 < KT_STEPS) STAGE(cur ^ 1, kt + 1);  // prefetch (no wait)

    bf16x8 af[4], bf[4];
#pragma unroll
    for (int mi = 0; mi < 4; ++mi)
      af[mi] = *reinterpret_cast<const bf16x8*>(
          &As[cur][(wr * 64 + mi * 16 + l15) * BK + ((l16 ^ swz) << 3)]);
#pragma unroll
    for (int ni = 0; ni < 4; ++ni)
      bf[ni] = *reinterpret_cast<const bf16x8*>(
          &Bs[cur][(wc * 64 + ni * 16 + l15) * BK + ((l16 ^ swz) << 3)]);
#pragma unroll
    for (int mi = 0; mi < 4; ++mi)
#pragma unroll
      for (int ni = 0; ni < 4; ++ni)
        acc[mi][ni] = __builtin_amdgcn_mfma_f32_16x16x32_bf16(
            af[mi], bf[ni], acc[mi][ni], 0, 0, 0);

    __syncthreads();  // drains vmcnt(0) (prefetch landed) + lgkm (reads done)
  }

  // ---- Epilogue: dual argmax from acc. C/D layout: col=lane&15,
  // row=(lane>>4)*4+reg. Key = mono(v)<<32 | ~idx  (max => first-occurrence).

  // Row side: max over this wave's 64 columns for each of its 64 rows.
#pragma unroll
  for (int mi = 0; mi < 4; ++mi)
#pragma unroll
    for (int j = 0; j < 4; ++j) {
      const int gi = mrow0 + wr * 64 + mi * 16 + l16 * 4 + j;
      unsigned long long key = 0ull;
#pragma unroll
      for (int ni = 0; ni < 4; ++ni) {
        const int gj = ncol0 + wc * 64 + ni * 16 + l15;
        if (gi != gj) {
          unsigned long long k =
              ((unsigned long long)mono_f32(acc[mi][ni][j]) << 32) |
              (unsigned int)(~gj);
          key = kmax(key, k);
        }
      }
#pragma unroll
      for (int m = 1; m < 16; m <<= 1)
        key = kmax(key, __shfl_xor(key, m));
      if (l15 == 0) atomicMax(&nn64[gi], key);
    }

  // Col side (symmetry): max over this wave's 64 rows for each of its 64 cols.
#pragma unroll
  for (int ni = 0; ni < 4; ++ni) {
    const int gj = ncol0 + wc * 64 + ni * 16 + l15;
    unsigned long long key = 0ull;
#pragma unroll
    for (int mi = 0; mi < 4; ++mi)
#pragma unroll
      for (int j = 0; j < 4; ++j) {
        const int gi = mrow0 + wr * 64 + mi * 16 + l16 * 4 + j;
        if (gi != gj) {
          unsigned long long k =
              ((unsigned long long)mono_f32(acc[mi][ni][j]) << 32) |
              (unsigned int)(~gi);
          key = kmax(key, k);
        }
      }
#pragma unroll
    for (int m = 16; m < 64; m <<= 1)
      key = kmax(key, __shfl_xor(key, m));
    if (l16 == 0) atomicMax(&nn64[gj], key);
  }
#undef STAGE
}

// rho_r = ||x_r - x_{nn(r)} + 1e-6||_2 ; logs[r] = log(rho + 1e-8).
__global__ void dist_log_kernel(const float* __restrict__ x,
                                const unsigned long long* __restrict__ nn64,
                                float* __restrict__ logs) {
  const int row  = blockIdx.x * 4 + (threadIdx.x >> 6);
  const int lane = threadIdx.x & 63;
  const int nn   = (int)(~(unsigned int)(nn64[row] & 0xFFFFFFFFull)) & (NPTS - 1);
  const float4* xr = reinterpret_cast<const float4*>(x + (size_t)row * DIM);
  const float4* xn = reinterpret_cast<const float4*>(x + (size_t)nn  * DIM);
  float s = 0.f;
#pragma unroll
  for (int i = 0; i < 2; ++i) {
    float4 a = xr[lane + i * 64];
    float4 b = xn[lane + i * 64];
    float d0 = a.x - b.x + 1e-6f;
    float d1 = a.y - b.y + 1e-6f;
    float d2 = a.z - b.z + 1e-6f;
    float d3 = a.w - b.w + 1e-6f;
    s += d0 * d0 + d1 * d1 + d2 * d2 + d3 * d3;
  }
#pragma unroll
  for (int m = 32; m >= 1; m >>= 1) s += __shfl_xor(s, m);
  if (lane == 0) logs[row] = logf(sqrtf(s) + 1e-8f);
}

// Deterministic mean: 1024 threads x 8 sequential adds + LDS tree.
__global__ void final_reduce_kernel(const float* __restrict__ logs,
                                    float* __restrict__ out) {
  __shared__ float sm[1024];
  const int t = threadIdx.x;
  float s = 0.f;
#pragma unroll
  for (int i = 0; i < 8; ++i) s += logs[t * 8 + i];
  sm[t] = s;
  __syncthreads();
  for (int k = 512; k > 0; k >>= 1) {
    if (t < k) sm[t] += sm[t + k];
    __syncthreads();
  }
  if (t == 0) out[0] = -(sm[0] / (float)NPTS);
}

extern "C" void kernel_launch(void* const* d_in, const int* in_sizes, int n_in,
                              void* d_out, int out_size, void* d_ws, size_t ws_size,
                              hipStream_t stream) {
  const float* x = (const float*)d_in[0];
  float* out = (float*)d_out;
  char* ws = (char*)d_ws;

  // Workspace layout (bytes):
  unsigned short*     xb   = (unsigned short*)(ws);           // 8 MB
  unsigned long long* nn64 = (unsigned long long*)(ws + 8388608); // 64 KB
  float*              logs = (float*)(ws + 8454144);          // 32 KB

  cvt_bf16_kernel<<<(NPTS * DIM / 4) / 256, 256, 0, stream>>>(x, xb, nn64);

  tri_gemm_kernel<<<NBLK, 256, 0, stream>>>(xb, nn64);

  dist_log_kernel<<<NPTS / 4, 256, 0, stream>>>(x, nn64, logs);

  final_reduce_kernel<<<1, 1024, 0, stream>>>(logs, out);
}

// Round 3
// 101.433 us; speedup vs baseline: 2.0612x; 1.2269x over previous
//
#include <hip/hip_runtime.h>

// n = 8192 points, d = 512, fp32 in, scalar fp32 out.
// Pipeline:
//   (1) fp32->bf16 convert (+ zero-init packed argmax keys)
//   (2) triangular-cover fused bf16-MFMA GEMM, 256x128 tiles, BK=64,
//       deep-pipelined (counted vmcnt, never 0) with dual row/col argmax
//       via deterministic u64 atomicMax of (monotone(value)<<32 | ~index)
//   (3) per-row ||x - x[I] + 1e-6||_2 -> log
//   (4) deterministic mean reduce.

#define NPTS 8192
#define DIM  512
#define BM   256
#define BN   128
#define BK   64
#define KT   (DIM / BK)                 // 8 K-tiles
#define NTI  (NPTS / BM)                // 32 row tiles
#define NBLK (NTI * (NTI + 1))          // sum_{ti<32}(2ti+2) = 1056
#define XCHUNK (NBLK / 8)               // 132 (bijective XCD swizzle)

typedef __bf16 bf16x8 __attribute__((ext_vector_type(8)));
typedef float  f32x4  __attribute__((ext_vector_type(4)));

__device__ __forceinline__ unsigned short f32_to_bf16(float f) {
  unsigned int u = __builtin_bit_cast(unsigned int, f);
  u += 0x7fffu + ((u >> 16) & 1u);   // round-to-nearest-even
  return (unsigned short)(u >> 16);
}

// Order-preserving f32 -> u32.
__device__ __forceinline__ unsigned int mono_f32(float f) {
  unsigned int u = __builtin_bit_cast(unsigned int, f);
  return (u & 0x80000000u) ? ~u : (u | 0x80000000u);
}

__global__ void cvt_bf16_kernel(const float* __restrict__ x,
                                unsigned short* __restrict__ xb,
                                unsigned long long* __restrict__ nn64) {
  int i = blockIdx.x * blockDim.x + threadIdx.x;      // 4 elems per thread
  float4 v = reinterpret_cast<const float4*>(x)[i];
  ushort4 o;
  o.x = f32_to_bf16(v.x); o.y = f32_to_bf16(v.y);
  o.z = f32_to_bf16(v.z); o.w = f32_to_bf16(v.w);
  reinterpret_cast<ushort4*>(xb)[i] = o;
  if (i < NPTS) nn64[i] = 0ull;                       // argmax key init
}

__device__ __forceinline__ void gload_lds16(const unsigned short* g,
                                            unsigned short* l) {
  __builtin_amdgcn_global_load_lds(
      (__attribute__((address_space(1))) const void*)g,
      (__attribute__((address_space(3))) void*)l, 16, 0, 0);
}

__device__ __forceinline__ unsigned long long kmax(unsigned long long a,
                                                   unsigned long long b) {
  return a > b ? a : b;
}

// Triangular-cover fused GEMM + dual argmax.
// grid = NBLK, block = 512 (8 waves in a 4x2 grid of 64x64 sub-tiles).
// Tile set: ti in [0,32), tj in [0, 2*ti+2)  (col range always <= row range
// end; upper-triangle spill of the last col tile is harmless extra coverage).
__global__ __launch_bounds__(512) void tri_gemm_kernel(
    const unsigned short* __restrict__ xb,
    unsigned long long* __restrict__ nn64) {
  __shared__ unsigned short As[2][BM * BK];   // 2 x 32 KB
  __shared__ unsigned short Bs[2][BN * BK];   // 2 x 16 KB

  // XCD-bijective swizzle, then block -> (ti, tj): cum(ti) = ti*(ti+1).
  int b = ((int)blockIdx.x & 7) * XCHUNK + ((int)blockIdx.x >> 3);
  int ti = (int)((sqrtf(4.0f * (float)b + 1.0f) - 1.0f) * 0.5f);
  while ((ti + 1) * (ti + 2) <= b) ++ti;
  while (ti * (ti + 1) > b) --ti;
  const int tj = b - ti * (ti + 1);

  const int tid  = (int)threadIdx.x;
  const int wid  = tid >> 6;
  const int lane = tid & 63;
  const int wr   = wid >> 1;       // 0..3  (64-row band within 256)
  const int wc   = wid & 1;        // 0..1  (64-col band within 128)
  const int l15  = lane & 15;
  const int l16  = lane >> 4;      // 0..3

  const int mrow0 = ti * BM;
  const int ncol0 = tj * BN;

  // --- staging: chunk = 16B = 8 bf16. Row has 8 chunks (BK=64).
  // LDS holds global chunk (s ^ (row&7)) at linear position s (involution)
  // so strided ds_read_b128 is ~2-way bank-conflict free.
#define A_LOAD(buf, kt, a_) do {                                             \
    const int chunk_ = ((a_) << 9) + tid;        /* 0..2047 */               \
    const int row_   = chunk_ >> 3;              /* 0..255 */                \
    const int s_     = chunk_ & 7;                                           \
    gload_lds16(xb + (size_t)(mrow0 + row_) * DIM + (kt) * BK +              \
                    ((s_ ^ (row_ & 7)) << 3),                                \
                &As[buf][chunk_ << 3]);                                      \
  } while (0)
#define B_LOAD(buf, kt, b_) do {                                             \
    const int chunk_ = ((b_) << 9) + tid;        /* 0..1023 */               \
    const int row_   = chunk_ >> 3;              /* 0..127 */                \
    const int s_     = chunk_ & 7;                                           \
    gload_lds16(xb + (size_t)(ncol0 + row_) * DIM + (kt) * BK +              \
                    ((s_ ^ (row_ & 7)) << 3),                                \
                &Bs[buf][chunk_ << 3]);                                      \
  } while (0)

  f32x4 acc[4][4];
#pragma unroll
  for (int mi = 0; mi < 4; ++mi)
#pragma unroll
    for (int ni = 0; ni < 4; ++ni)
      acc[mi][ni] = (f32x4){0.f, 0.f, 0.f, 0.f};

  // Fragment LDS element offsets (row&7 == l15&7 since bands are x16):
  // offset(row, kk) = row*64 + ((kk*4 + l16) ^ (l15&7)) * 8
  const int sw = l15 & 7;
  int aoff[4], boff[4];
#pragma unroll
  for (int mi = 0; mi < 4; ++mi)
    aoff[mi] = (wr * 64 + mi * 16 + l15) * 64;
#pragma unroll
  for (int ni = 0; ni < 4; ++ni)
    boff[ni] = (wc * 64 + ni * 16 + l15) * 64;

  // Prologue: stage K-tile 0 into buf 0 (6 loads), no wait here.
  A_LOAD(0, 0, 0); A_LOAD(0, 0, 1); B_LOAD(0, 0, 0);
  A_LOAD(0, 0, 2); A_LOAD(0, 0, 3); B_LOAD(0, 0, 1);

  for (int t = 0; t < KT; ++t) {
    const int cur = t & 1;
    const int nxt = cur ^ 1;
    const int tn  = (t + 1 < KT) ? t + 1 : 0;   // last-iter stage is dummy

    // ---- phase 0: issue 3 prefetch loads, counted wait, publish barrier,
    //      consume kk=0 half.
    A_LOAD(nxt, tn, 0); A_LOAD(nxt, tn, 1); B_LOAD(nxt, tn, 0);
    asm volatile("s_waitcnt vmcnt(3)" ::: "memory");  // tile t's 6 loads done
    asm volatile("s_barrier" ::: "memory");           // all waves agree

    {
      bf16x8 af[4], bf[4];
#pragma unroll
      for (int mi = 0; mi < 4; ++mi)
        af[mi] = *reinterpret_cast<const bf16x8*>(
            &As[cur][aoff[mi] + ((l16 ^ sw) << 3)]);
#pragma unroll
      for (int ni = 0; ni < 4; ++ni)
        bf[ni] = *reinterpret_cast<const bf16x8*>(
            &Bs[cur][boff[ni] + ((l16 ^ sw) << 3)]);
      __builtin_amdgcn_s_setprio(1);
#pragma unroll
      for (int mi = 0; mi < 4; ++mi)
#pragma unroll
        for (int ni = 0; ni < 4; ++ni)
          acc[mi][ni] = __builtin_amdgcn_mfma_f32_16x16x32_bf16(
              af[mi], bf[ni], acc[mi][ni], 0, 0, 0);
      __builtin_amdgcn_s_setprio(0);
    }

    // ---- phase 1: issue remaining 3 prefetch loads, consume kk=1 half.
    A_LOAD(nxt, tn, 2); A_LOAD(nxt, tn, 3); B_LOAD(nxt, tn, 1);
    {
      bf16x8 af[4], bf[4];
#pragma unroll
      for (int mi = 0; mi < 4; ++mi)
        af[mi] = *reinterpret_cast<const bf16x8*>(
            &As[cur][aoff[mi] + (((4 + l16) ^ sw) << 3)]);
#pragma unroll
      for (int ni = 0; ni < 4; ++ni)
        bf[ni] = *reinterpret_cast<const bf16x8*>(
            &Bs[cur][boff[ni] + (((4 + l16) ^ sw) << 3)]);
      __builtin_amdgcn_s_setprio(1);
#pragma unroll
      for (int mi = 0; mi < 4; ++mi)
#pragma unroll
        for (int ni = 0; ni < 4; ++ni)
          acc[mi][ni] = __builtin_amdgcn_mfma_f32_16x16x32_bf16(
              af[mi], bf[ni], acc[mi][ni], 0, 0, 0);
      __builtin_amdgcn_s_setprio(0);
    }

    // End-of-tile: all waves finished reading buf[cur] (reads complete
    // before the MFMAs above) before tile t+1 issues writes into it.
    asm volatile("s_barrier" ::: "memory");
  }
#undef A_LOAD
#undef B_LOAD

  // ---- Epilogue: dual argmax from acc. C/D layout: col=lane&15,
  // row=(lane>>4)*4+reg. Key = mono(v)<<32 | ~idx (max => first occurrence).

  // Row side: per output row, max over this wave's 64 columns.
#pragma unroll
  for (int mi = 0; mi < 4; ++mi)
#pragma unroll
    for (int j = 0; j < 4; ++j) {
      const int gi = mrow0 + wr * 64 + mi * 16 + l16 * 4 + j;
      unsigned long long key = 0ull;
#pragma unroll
      for (int ni = 0; ni < 4; ++ni) {
        const int gj = ncol0 + wc * 64 + ni * 16 + l15;
        if (gi != gj) {
          unsigned long long k =
              ((unsigned long long)mono_f32(acc[mi][ni][j]) << 32) |
              (unsigned int)(~gj);
          key = kmax(key, k);
        }
      }
#pragma unroll
      for (int m = 1; m < 16; m <<= 1)
        key = kmax(key, __shfl_xor(key, m));
      if (l15 == 0) atomicMax(&nn64[gi], key);
    }

  // Col side (symmetry): per output col, max over this wave's 64 rows.
#pragma unroll
  for (int ni = 0; ni < 4; ++ni) {
    const int gj = ncol0 + wc * 64 + ni * 16 + l15;
    unsigned long long key = 0ull;
#pragma unroll
    for (int mi = 0; mi < 4; ++mi)
#pragma unroll
      for (int j = 0; j < 4; ++j) {
        const int gi = mrow0 + wr * 64 + mi * 16 + l16 * 4 + j;
        if (gi != gj) {
          unsigned long long k =
              ((unsigned long long)mono_f32(acc[mi][ni][j]) << 32) |
              (unsigned int)(~gi);
          key = kmax(key, k);
        }
      }
#pragma unroll
    for (int m = 16; m < 64; m <<= 1)
      key = kmax(key, __shfl_xor(key, m));
    if (l16 == 0) atomicMax(&nn64[gj], key);
  }
}

// rho_r = ||x_r - x_{nn(r)} + 1e-6||_2 ; logs[r] = log(rho + 1e-8).
__global__ void dist_log_kernel(const float* __restrict__ x,
                                const unsigned long long* __restrict__ nn64,
                                float* __restrict__ logs) {
  const int row  = blockIdx.x * 4 + ((int)threadIdx.x >> 6);
  const int lane = (int)threadIdx.x & 63;
  const int nn   = (int)(~(unsigned int)(nn64[row] & 0xFFFFFFFFull)) & (NPTS - 1);
  const float4* xr = reinterpret_cast<const float4*>(x + (size_t)row * DIM);
  const float4* xn = reinterpret_cast<const float4*>(x + (size_t)nn  * DIM);
  float s = 0.f;
#pragma unroll
  for (int i = 0; i < 2; ++i) {
    float4 a = xr[lane + i * 64];
    float4 b = xn[lane + i * 64];
    float d0 = a.x - b.x + 1e-6f;
    float d1 = a.y - b.y + 1e-6f;
    float d2 = a.z - b.z + 1e-6f;
    float d3 = a.w - b.w + 1e-6f;
    s += d0 * d0 + d1 * d1 + d2 * d2 + d3 * d3;
  }
#pragma unroll
  for (int m = 32; m >= 1; m >>= 1) s += __shfl_xor(s, m);
  if (lane == 0) logs[row] = logf(sqrtf(s) + 1e-8f);
}

// Deterministic mean: 1024 threads x 8 sequential adds + LDS tree.
__global__ void final_reduce_kernel(const float* __restrict__ logs,
                                    float* __restrict__ out) {
  __shared__ float sm[1024];
  const int t = (int)threadIdx.x;
  float s = 0.f;
#pragma unroll
  for (int i = 0; i < 8; ++i) s += logs[t * 8 + i];
  sm[t] = s;
  __syncthreads();
  for (int k = 512; k > 0; k >>= 1) {
    if (t < k) sm[t] += sm[t + k];
    __syncthreads();
  }
  if (t == 0) out[0] = -(sm[0] / (float)NPTS);
}

extern "C" void kernel_launch(void* const* d_in, const int* in_sizes, int n_in,
                              void* d_out, int out_size, void* d_ws, size_t ws_size,
                              hipStream_t stream) {
  const float* x = (const float*)d_in[0];
  float* out = (float*)d_out;
  char* ws = (char*)d_ws;

  // Workspace layout (bytes):
  unsigned short*     xb   = (unsigned short*)(ws);               // 8 MB
  unsigned long long* nn64 = (unsigned long long*)(ws + 8388608); // 64 KB
  float*              logs = (float*)(ws + 8454144);              // 32 KB

  cvt_bf16_kernel<<<(NPTS * DIM / 4) / 256, 256, 0, stream>>>(x, xb, nn64);

  tri_gemm_kernel<<<NBLK, 512, 0, stream>>>(xb, nn64);

  dist_log_kernel<<<NPTS / 4, 256, 0, stream>>>(x, nn64, logs);

  final_reduce_kernel<<<1, 1024, 0, stream>>>(logs, out);
}

// Round 4
// 75.742 us; speedup vs baseline: 2.7603x; 1.3392x over previous
//
#include <hip/hip_runtime.h>

// n = 8192 points, d = 512, fp32 in, scalar fp32 out.
// Pipeline:
//   (1) fp32->bf16 convert (+ zero-init packed argmax keys)
//   (2) triangular-cover strip-fused bf16-MFMA GEMM: each block = row tile
//       (128 rows) x strip of <=3 col tiles; 128x128 tiles, BK=32, triple-
//       buffered LDS, depth-2 counted-vmcnt pipeline. Row-argmax kept in
//       registers across the strip (flushed once); col-argmax flushed per
//       tile. Merging via deterministic u64 atomicMax of
//       (monotone(value)<<32 | ~index)  -> exact first-occurrence ties.
//   (3) per-row ||x - x[I] + 1e-6||_2 -> log
//   (4) deterministic mean reduce.

#define NPTS 8192
#define DIM  512
#define BM   128
#define BN   128
#define BK   32
#define NROWT (NPTS / BM)    // 64 row tiles
#define NBLK  715            // sum_{r=0}^{63} ceil((r+1)/3)

typedef __bf16 bf16x8 __attribute__((ext_vector_type(8)));
typedef float  f32x4  __attribute__((ext_vector_type(4)));

__device__ __forceinline__ unsigned short f32_to_bf16(float f) {
  unsigned int u = __builtin_bit_cast(unsigned int, f);
  u += 0x7fffu + ((u >> 16) & 1u);   // round-to-nearest-even
  return (unsigned short)(u >> 16);
}

// Order-preserving f32 -> u32.
__device__ __forceinline__ unsigned int mono_f32(float f) {
  unsigned int u = __builtin_bit_cast(unsigned int, f);
  return (u & 0x80000000u) ? ~u : (u | 0x80000000u);
}

__global__ void cvt_bf16_kernel(const float* __restrict__ x,
                                unsigned short* __restrict__ xb,
                                unsigned long long* __restrict__ nn64) {
  int i = blockIdx.x * blockDim.x + threadIdx.x;      // 4 elems per thread
  float4 v = reinterpret_cast<const float4*>(x)[i];
  ushort4 o;
  o.x = f32_to_bf16(v.x); o.y = f32_to_bf16(v.y);
  o.z = f32_to_bf16(v.z); o.w = f32_to_bf16(v.w);
  reinterpret_cast<ushort4*>(xb)[i] = o;
  if (i < NPTS) nn64[i] = 0ull;                       // argmax key init
}

__device__ __forceinline__ void gload_lds16(const unsigned short* g,
                                            unsigned short* l) {
  __builtin_amdgcn_global_load_lds(
      (__attribute__((address_space(1))) const void*)g,
      (__attribute__((address_space(3))) void*)l, 16, 0, 0);
}

// Chunks (strips of 3 col-tiles) in rows [0, ti).
__device__ __forceinline__ int chunk_prefix(int ti) {
  int q = ti / 3, s = ti - 3 * q;
  return ti + 3 * q * (q - 1) / 2 + s * q;
}

// Strip-fused triangular GEMM + dual argmax.
// grid = NBLK, block = 256 (4 waves, 2x2 grid of 64x64 sub-tiles).
__global__ __launch_bounds__(256, 3) void tri_gemm_kernel(
    const unsigned short* __restrict__ xb,
    unsigned long long* __restrict__ nn64) {
  __shared__ unsigned short As[3][BM * BK];   // 3 x 8 KB
  __shared__ unsigned short Bs[3][BN * BK];   // 3 x 8 KB

  // Bijective XCD swizzle (nwg = 715 = 8*89 + 3).
  const int q8 = NBLK >> 3, r8 = NBLK & 7;
  const int orig = (int)blockIdx.x;
  const int xcd = orig & 7, loc = orig >> 3;
  int b = (xcd < r8 ? xcd * (q8 + 1) : r8 * (q8 + 1) + (xcd - r8) * q8) + loc;

  // b -> (ti, tj0, ntiles)
  int ti = (int)sqrtf(6.0f * (float)b + 1.0f);
  if (ti > NROWT - 1) ti = NROWT - 1;
  while (chunk_prefix(ti) > b) --ti;
  while (chunk_prefix(ti + 1) <= b) ++ti;
  const int tj0 = 3 * (b - chunk_prefix(ti));
  const int ntiles = min(3, ti + 1 - tj0);
  const int U = ntiles << 4;                  // 16 K-steps per tile

  const int tid  = (int)threadIdx.x;
  const int wid  = tid >> 6;
  const int lane = tid & 63;
  const int wr   = wid >> 1;      // 0..1
  const int wc   = wid & 1;       // 0..1
  const int l15  = lane & 15;
  const int l16  = lane >> 4;     // 0..3
  const int arow0 = ti * BM;
  const int swz  = (l15 >> 1) & 3;

  // Stage K-step v (tile v>>4, K-chunk v&15) into buffer bufi.
  // Source-side XOR swizzle (chunk s ^ ((row>>1)&3)) => conflict-free reads.
#define STAGE(bufi, v) do {                                                  \
    const int kt_ = ((v) & 15) * BK;                                         \
    const int bc_ = (tj0 + ((v) >> 4)) * BN;                                 \
    _Pragma("unroll")                                                        \
    for (int i_ = 0; i_ < 2; ++i_) {                                         \
      const int chunk_ = (i_ << 8) + tid;          /* 0..511 (16B) */        \
      const int row_   = chunk_ >> 2;              /* 0..127 */              \
      const int sg_    = (chunk_ & 3) ^ ((row_ >> 1) & 3);                   \
      const int lb_    = ((i_ << 8) + (wid << 6)) << 3; /* wave-uniform */   \
      gload_lds16(xb + (size_t)(arow0 + row_) * DIM + kt_ + (sg_ << 3),      \
                  &As[bufi][lb_]);                                           \
      gload_lds16(xb + (size_t)(bc_ + row_) * DIM + kt_ + (sg_ << 3),        \
                  &Bs[bufi][lb_]);                                           \
    }                                                                        \
  } while (0)

  float best[16];
  int   bidx[16];
#pragma unroll
  for (int i = 0; i < 16; ++i) { best[i] = -1e30f; bidx[i] = 0; }

  f32x4 acc[4][4];
#pragma unroll
  for (int mi = 0; mi < 4; ++mi)
#pragma unroll
    for (int ni = 0; ni < 4; ++ni)
      acc[mi][ni] = (f32x4){0.f, 0.f, 0.f, 0.f};

  int aoff[4], boff[4];
#pragma unroll
  for (int mi = 0; mi < 4; ++mi)
    aoff[mi] = (wr * 64 + mi * 16 + l15) * BK;
#pragma unroll
  for (int ni = 0; ni < 4; ++ni)
    boff[ni] = (wc * 64 + ni * 16 + l15) * BK;

  // Prologue: 2 K-steps in flight.
  STAGE(0, 0);
  STAGE(1, 1);

  int br = 0, bs = 2;
  for (int u = 0; u < U; ++u) {
    if (u + 2 < U) {
      STAGE(bs, u + 2);
      asm volatile("s_waitcnt vmcnt(8)" ::: "memory");   // step u's loads done
    } else if (u + 2 == U) {
      asm volatile("s_waitcnt vmcnt(4)" ::: "memory");
    } else {
      asm volatile("s_waitcnt vmcnt(0)" ::: "memory");
    }
    asm volatile("s_barrier" ::: "memory");              // buf[br] published

    bf16x8 af[4], bf[4];
#pragma unroll
    for (int mi = 0; mi < 4; ++mi)
      af[mi] = *reinterpret_cast<const bf16x8*>(
          &As[br][aoff[mi] + ((l16 ^ swz) << 3)]);
#pragma unroll
    for (int ni = 0; ni < 4; ++ni)
      bf[ni] = *reinterpret_cast<const bf16x8*>(
          &Bs[br][boff[ni] + ((l16 ^ swz) << 3)]);
    __builtin_amdgcn_s_setprio(1);
#pragma unroll
    for (int mi = 0; mi < 4; ++mi)
#pragma unroll
      for (int ni = 0; ni < 4; ++ni)
        acc[mi][ni] = __builtin_amdgcn_mfma_f32_16x16x32_bf16(
            af[mi], bf[ni], acc[mi][ni], 0, 0, 0);
    __builtin_amdgcn_s_setprio(0);

    if ((u & 15) == 15) {   // tile complete: update argmaxes, reset acc
      const int bc0 = (tj0 + (u >> 4)) * BN;
      // Row side: running register argmax (strict > + ascending cols
      // == first occurrence).
#pragma unroll
      for (int mi = 0; mi < 4; ++mi)
#pragma unroll
        for (int j = 0; j < 4; ++j) {
          const int slot = mi * 4 + j;
          const int gi = arow0 + wr * 64 + mi * 16 + l16 * 4 + j;
#pragma unroll
          for (int ni = 0; ni < 4; ++ni) {
            float v = acc[mi][ni][j];
            const int gj = bc0 + wc * 64 + ni * 16 + l15;
            if (gj == gi) v = -1e30f;            // mask diagonal
            if (v > best[slot]) { best[slot] = v; bidx[slot] = gj; }
          }
        }
      // Col side (symmetry): reduce over the wave's 64 rows, flush now.
#pragma unroll
      for (int ni = 0; ni < 4; ++ni) {
        const int gj = bc0 + wc * 64 + ni * 16 + l15;
        float cv = -1e30f; int ci = 0;
#pragma unroll
        for (int mi = 0; mi < 4; ++mi)
#pragma unroll
          for (int j = 0; j < 4; ++j) {
            float v = acc[mi][ni][j];
            const int gi = arow0 + wr * 64 + mi * 16 + l16 * 4 + j;
            if (gi == gj) v = -1e30f;
            if (v > cv) { cv = v; ci = gi; }     // ascending gi => first occ.
          }
#pragma unroll
        for (int m = 16; m < 64; m <<= 1) {
          float ov = __shfl_xor(cv, m);
          int   oi = __shfl_xor(ci, m);
          if (ov > cv || (ov == cv && oi < ci)) { cv = ov; ci = oi; }
        }
        if (l16 == 0)
          atomicMax(&nn64[gj],
                    ((unsigned long long)mono_f32(cv) << 32) |
                        (unsigned int)(~ci));
      }
      // Reset accumulators for the next tile.
#pragma unroll
      for (int mi = 0; mi < 4; ++mi)
#pragma unroll
        for (int ni = 0; ni < 4; ++ni)
          acc[mi][ni] = (f32x4){0.f, 0.f, 0.f, 0.f};
    }

    asm volatile("s_barrier" ::: "memory");   // reads of buf[br] done
    br = (br + 1 == 3) ? 0 : br + 1;
    bs = (bs + 1 == 3) ? 0 : bs + 1;
  }
#undef STAGE

  // Strip-end row-side flush: reduce over the 16 lanes sharing each row.
#pragma unroll
  for (int mi = 0; mi < 4; ++mi)
#pragma unroll
    for (int j = 0; j < 4; ++j) {
      const int slot = mi * 4 + j;
      float bv = best[slot]; int bi = bidx[slot];
#pragma unroll
      for (int m = 1; m < 16; m <<= 1) {
        float ov = __shfl_xor(bv, m);
        int   oi = __shfl_xor(bi, m);
        if (ov > bv || (ov == bv && oi < bi)) { bv = ov; bi = oi; }
      }
      if (l15 == 0) {
        const int gi = arow0 + wr * 64 + mi * 16 + l16 * 4 + j;
        atomicMax(&nn64[gi],
                  ((unsigned long long)mono_f32(bv) << 32) |
                      (unsigned int)(~bi));
      }
    }
}

// rho_r = ||x_r - x_{nn(r)} + 1e-6||_2 ; logs[r] = log(rho + 1e-8).
__global__ void dist_log_kernel(const float* __restrict__ x,
                                const unsigned long long* __restrict__ nn64,
                                float* __restrict__ logs) {
  const int row  = blockIdx.x * 4 + ((int)threadIdx.x >> 6);
  const int lane = (int)threadIdx.x & 63;
  const int nn   = (int)(~(unsigned int)(nn64[row] & 0xFFFFFFFFull)) & (NPTS - 1);
  const float4* xr = reinterpret_cast<const float4*>(x + (size_t)row * DIM);
  const float4* xn = reinterpret_cast<const float4*>(x + (size_t)nn  * DIM);
  float s = 0.f;
#pragma unroll
  for (int i = 0; i < 2; ++i) {
    float4 a = xr[lane + i * 64];
    float4 b = xn[lane + i * 64];
    float d0 = a.x - b.x + 1e-6f;
    float d1 = a.y - b.y + 1e-6f;
    float d2 = a.z - b.z + 1e-6f;
    float d3 = a.w - b.w + 1e-6f;
    s += d0 * d0 + d1 * d1 + d2 * d2 + d3 * d3;
  }
#pragma unroll
  for (int m = 32; m >= 1; m >>= 1) s += __shfl_xor(s, m);
  if (lane == 0) logs[row] = logf(sqrtf(s) + 1e-8f);
}

// Deterministic mean: 1024 threads x 8 sequential adds + LDS tree.
__global__ void final_reduce_kernel(const float* __restrict__ logs,
                                    float* __restrict__ out) {
  __shared__ float sm[1024];
  const int t = (int)threadIdx.x;
  float s = 0.f;
#pragma unroll
  for (int i = 0; i < 8; ++i) s += logs[t * 8 + i];
  sm[t] = s;
  __syncthreads();
  for (int k = 512; k > 0; k >>= 1) {
    if (t < k) sm[t] += sm[t + k];
    __syncthreads();
  }
  if (t == 0) out[0] = -(sm[0] / (float)NPTS);
}

extern "C" void kernel_launch(void* const* d_in, const int* in_sizes, int n_in,
                              void* d_out, int out_size, void* d_ws, size_t ws_size,
                              hipStream_t stream) {
  const float* x = (const float*)d_in[0];
  float* out = (float*)d_out;
  char* ws = (char*)d_ws;

  // Workspace layout (bytes):
  unsigned short*     xb   = (unsigned short*)(ws);               // 8 MB
  unsigned long long* nn64 = (unsigned long long*)(ws + 8388608); // 64 KB
  float*              logs = (float*)(ws + 8454144);              // 32 KB

  cvt_bf16_kernel<<<(NPTS * DIM / 4) / 256, 256, 0, stream>>>(x, xb, nn64);

  tri_gemm_kernel<<<NBLK, 256, 0, stream>>>(xb, nn64);

  dist_log_kernel<<<NPTS / 4, 256, 0, stream>>>(x, nn64, logs);

  final_reduce_kernel<<<1, 1024, 0, stream>>>(logs, out);
}